// Round 3
// baseline (1794.856 us; speedup 1.0000x reference)
//
#include <hip/hip_runtime.h>

// FPS + gather, B=16, N=65536, S=512, C=64.
// 16 WGs/batch, 4096-pt chunk in registers. Per-iteration cross-WG exchange:
// each WG's winning THREAD swaps 4 self-validating tagged words
// {tag|dist|~idx, tag|x, tag|y, tag|z} into IF$-coherent slots (atomic swap =
// immediate visibility, no write-combine laziness). All waves poll one
// coalesced 512B load and reduce via shuffles -- single __syncthreads per
// iteration, centroid delivered by the exchange itself (no dependent fetch).

#define NB   16
#define NPTS 65536
#define NS   512
#define WPB  16                 // workgroups (and slots) per batch
#define CHUNK (NPTS / WPB)      // 4096 points per WG
#define NTHR 256
#define PPT  (CHUNK / NTHR)     // 16 points per thread
#define NWAVE 4
#define SPW  (NS / WPB)         // 32 samples gathered per WG
#define SLOTW (4 * WPB)         // 64 u64 words per (parity,batch) region

// Exact fp32, reference op order, no FMA contraction:
__device__ __forceinline__ float sqdist3(float x, float y, float z,
                                         float cx, float cy, float cz) {
    float dx = __fsub_rn(x, cx);
    float dy = __fsub_rn(y, cy);
    float dz = __fsub_rn(z, cz);
    return __fadd_rn(__fadd_rn(__fmul_rn(dx, dx), __fmul_rn(dy, dy)),
                     __fmul_rn(dz, dz));
}

__global__ void __launch_bounds__(NTHR, 1)
fps_kernel(const float* __restrict__ xyz, const float* __restrict__ feat,
           float* __restrict__ out, unsigned long long* __restrict__ slots) {
    const int wg   = blockIdx.x & (WPB - 1);
    const int b    = blockIdx.x / WPB;
    const int tid  = threadIdx.x;
    const int lane = tid & 63;
    const int wave = tid >> 6;

    __shared__ int sel[NS];
    __shared__ unsigned long long wmax[NWAVE];

    const float* bx  = xyz + (size_t)b * NPTS * 3;
    const int   base = wg * CHUNK;

    float rx[PPT], ry[PPT], rz[PPT], dmin[PPT];
#pragma unroll
    for (int k = 0; k < PPT; ++k) {
        int g = base + tid + k * NTHR;
        rx[k] = bx[3 * g + 0];
        ry[k] = bx[3 * g + 1];
        rz[k] = bx[3 * g + 2];
        dmin[k] = 1e10f;                              // reference BIG
    }

    float cx = bx[0], cy = bx[1], cz = bx[2];         // seed centroid (pt 0)
    if (tid == 0) sel[0] = 0;

    for (int it = 1; it < NS; ++it) {
        // ---- local scan (exact ref order) ----
        float bd = -1.0f; int bi = 0;
#pragma unroll
        for (int k = 0; k < PPT; ++k) {
            float d  = sqdist3(rx[k], ry[k], rz[k], cx, cy, cz);
            float dm = fminf(dmin[k], d);
            dmin[k] = dm;
            if (dm > bd) { bd = dm; bi = base + tid + k * NTHR; }
        }
        // packed: [47:16]=dist bits (>=0 so monotone), [15:0]=0xFFFF-idx
        unsigned long long packed =
            ((unsigned long long)__float_as_uint(bd) << 16) |
            (unsigned long long)(0xFFFF - bi);
        // wave butterfly max (all lanes converge)
        unsigned long long wv = packed;
        for (int off = 1; off < 64; off <<= 1) {
            unsigned long long o = __shfl_xor(wv, off, 64);
            if (o > wv) wv = o;
        }
        if (lane == 0) wmax[wave] = wv;
        __syncthreads();
        unsigned long long m0 = wmax[0], m1 = wmax[1];
        unsigned long long m2 = wmax[2], m3 = wmax[3];
        if (m1 > m0) m0 = m1;
        if (m3 > m2) m2 = m3;
        if (m2 > m0) m0 = m2;                         // WG winner (all threads)

        unsigned long long* sb =
            slots + ((size_t)(it & 1) * NB + b) * SLOTW;

        if (packed == m0) {                           // unique owning thread
            int g = 0xFFFF - (int)(m0 & 0xFFFFull);
            int k = (g - base - tid) >> 8;            // /NTHR
            float wx = rx[0], wy = ry[0], wz = rz[0];
#pragma unroll
            for (int j = 1; j < PPT; ++j)
                if (j == k) { wx = rx[j]; wy = ry[j]; wz = rz[j]; }
            unsigned long long tag = (unsigned long long)it << 48;
            // word-major layout: word w of slot s at sb[w*WPB + s]
            __hip_atomic_exchange(&sb[0 * WPB + wg], tag | m0,
                                  __ATOMIC_RELAXED, __HIP_MEMORY_SCOPE_AGENT);
            __hip_atomic_exchange(&sb[1 * WPB + wg],
                                  tag | (unsigned long long)__float_as_uint(wx),
                                  __ATOMIC_RELAXED, __HIP_MEMORY_SCOPE_AGENT);
            __hip_atomic_exchange(&sb[2 * WPB + wg],
                                  tag | (unsigned long long)__float_as_uint(wy),
                                  __ATOMIC_RELAXED, __HIP_MEMORY_SCOPE_AGENT);
            __hip_atomic_exchange(&sb[3 * WPB + wg],
                                  tag | (unsigned long long)__float_as_uint(wz),
                                  __ATOMIC_RELAXED, __HIP_MEMORY_SCOPE_AGENT);
        }

        // ---- poll: lane l watches word l (one coalesced 512B wave-load) ----
        unsigned long long v;
        for (;;) {
            v = __hip_atomic_load(&sb[lane], __ATOMIC_RELAXED,
                                  __HIP_MEMORY_SCOPE_AGENT);
            if ((v >> 48) == (unsigned long long)it) break;
        }
        // slot s: word0 at lane s, x at 16+s, y at 32+s, z at 48+s
        int sidx = lane & 15;
        unsigned long long cand = __shfl(v, sidx, 64);
        int ws = sidx;
        for (int off = 1; off < 16; off <<= 1) {
            unsigned long long oc = __shfl_xor(cand, off, 64);
            int               os = __shfl_xor(ws, off, 64);
            if (oc > cand) { cand = oc; ws = os; }
        }
        cx = __uint_as_float((unsigned)__shfl(v, 16 + ws, 64));
        cy = __uint_as_float((unsigned)__shfl(v, 32 + ws, 64));
        cz = __uint_as_float((unsigned)__shfl(v, 48 + ws, 64));
        if (tid == 0) sel[it] = 0xFFFF - (int)(cand & 0xFFFFull);
    }
    __syncthreads();

    // ---- gather: this WG writes samples [wg*32, wg*32+32) ----
    const float* bf   = feat + (size_t)b * NPTS * 64;
    float*       oxyz = out + (size_t)b * NS * 3;
    float*       of   = out + (size_t)NB * NS * 3 + (size_t)b * NS * 64;
    const int c  = tid & 63;
    const int sr = tid >> 6;
    for (int k = 0; k < SPW / NWAVE; ++k) {
        int s = wg * SPW + k * NWAVE + sr;
        int p = sel[s];
        of[(size_t)s * 64 + c] = bf[(size_t)p * 64 + c];
    }
    if (tid < SPW * 3) {
        int s    = wg * SPW + tid / 3;
        int comp = tid % 3;
        oxyz[s * 3 + comp] = bx[sel[s] * 3 + comp];
    }
}

extern "C" void kernel_launch(void* const* d_in, const int* in_sizes, int n_in,
                              void* d_out, int out_size, void* d_ws, size_t ws_size,
                              hipStream_t stream) {
    const float* xyz = (const float*)d_in[0];
    const float* f   = (const float*)d_in[1];
    float* out = (float*)d_out;
    unsigned long long* slots = (unsigned long long*)d_ws;
    // Clear tags (tag 0 never matches it>=1). 2 parities x 16 batches x 64 words.
    hipMemsetAsync(d_ws, 0, (size_t)2 * NB * SLOTW * sizeof(unsigned long long),
                   stream);
    fps_kernel<<<dim3(NB * WPB), dim3(NTHR), 0, stream>>>(xyz, f, out, slots);
}

// Round 4
// 1663.160 us; speedup vs baseline: 1.0792x; 1.0792x over previous
//
#include <hip/hip_runtime.h>

// FPS + gather, B=16, N=65536, S=512, C=64.
// 16 WGs/batch, 4096-pt chunk in registers (48 VGPR). Per-iteration cross-WG
// exchange: the WG's winning THREAD publishes 4 self-validating tagged words
// {tag|dist|~idx, tag|x, tag|y, tag|z} with plain RELAXED atomic stores
// (RMW swap = write-through+invalidate on gfx950 -> polls miss to HBM; R3
// counter evidence: FETCH 20->52MB, WRITE 6->18MB). Each word lives on its
// own 128B line; all 4 waves poll (lane l -> word l) and reduce redundantly
// via shuffles, so the centroid arrives in-register with no LDS broadcast
// and a single __syncthreads per iteration.

#define NB    16
#define NPTS  65536
#define NS    512
#define WPB   16                 // workgroups (slots) per batch
#define CHUNK (NPTS / WPB)       // 4096 points per WG
#define NTHR  256
#define PPT   (CHUNK / NTHR)     // 16 points per thread
#define NWAVE 4
#define SPW   (NS / WPB)         // 32 samples gathered per WG
#define LINE_U64 16              // 128B line granularity
// per (parity,batch) region: 64 words (4 per slot), one per 128B line
#define REGION_U64 (64 * LINE_U64)

typedef unsigned long long u64;

// Exact fp32, reference op order, no FMA contraction:
__device__ __forceinline__ float sqdist3(float x, float y, float z,
                                         float cx, float cy, float cz) {
    float dx = __fsub_rn(x, cx);
    float dy = __fsub_rn(y, cy);
    float dz = __fsub_rn(z, cz);
    return __fadd_rn(__fadd_rn(__fmul_rn(dx, dx), __fmul_rn(dy, dy)),
                     __fmul_rn(dz, dz));
}

__global__ void __launch_bounds__(NTHR, 1)
fps_kernel(const float* __restrict__ xyz, const float* __restrict__ feat,
           float* __restrict__ out, u64* __restrict__ slots) {
    const int wg   = blockIdx.x & (WPB - 1);
    const int b    = blockIdx.x / WPB;
    const int tid  = threadIdx.x;
    const int lane = tid & 63;
    const int wave = tid >> 6;

    __shared__ int sel[NS];
    __shared__ u64 wmax[NWAVE];

    const float* bx  = xyz + (size_t)b * NPTS * 3;
    const int   base = wg * CHUNK;

    float rx[PPT], ry[PPT], rz[PPT], dmin[PPT];
#pragma unroll
    for (int k = 0; k < PPT; ++k) {
        int g = base + tid + k * NTHR;
        rx[k] = bx[3 * g + 0];
        ry[k] = bx[3 * g + 1];
        rz[k] = bx[3 * g + 2];
        dmin[k] = 1e10f;                              // reference BIG
    }

    float cx = bx[0], cy = bx[1], cz = bx[2];         // seed centroid (pt 0)
    if (tid == 0) sel[0] = 0;

    for (int it = 1; it < NS; ++it) {
        // ---- local scan (exact ref order) ----
        float bd = -1.0f; int bi = 0;
#pragma unroll
        for (int k = 0; k < PPT; ++k) {
            float d  = sqdist3(rx[k], ry[k], rz[k], cx, cy, cz);
            float dm = fminf(dmin[k], d);
            dmin[k] = dm;
            if (dm > bd) { bd = dm; bi = base + tid + k * NTHR; }
        }
        // packed: [47:16]=dist bits (>=0 after k=0, monotone), [15:0]=0xFFFF-idx
        u64 packed = ((u64)__float_as_uint(bd) << 16) |
                     (u64)(0xFFFF - bi);
        u64 wv = packed;
        for (int off = 1; off < 64; off <<= 1) {
            u64 o = __shfl_xor(wv, off, 64);
            if (o > wv) wv = o;
        }
        if (lane == 0) wmax[wave] = wv;
        __syncthreads();                               // the one barrier/iter
        u64 m0 = wmax[0], m1 = wmax[1], m2 = wmax[2], m3 = wmax[3];
        if (m1 > m0) m0 = m1;
        if (m3 > m2) m2 = m3;
        if (m2 > m0) m0 = m2;                          // WG winner (all threads)

        u64* sb = slots + ((size_t)(it & 1) * NB + b) * REGION_U64;

        if (packed == m0) {                            // unique owning thread
            int g = 0xFFFF - (int)(m0 & 0xFFFFull);
            int k = (g - base - tid) >> 8;             // / NTHR
            float wx = rx[0], wy = ry[0], wz = rz[0];
#pragma unroll
            for (int j = 1; j < PPT; ++j)
                if (j == k) { wx = rx[j]; wy = ry[j]; wz = rz[j]; }
            u64 tag = (u64)it << 48;
            // word w of slot s on its own line: line index = w*16 + s
            __hip_atomic_store(&sb[(0 * WPB + wg) * LINE_U64], tag | m0,
                               __ATOMIC_RELAXED, __HIP_MEMORY_SCOPE_AGENT);
            __hip_atomic_store(&sb[(1 * WPB + wg) * LINE_U64],
                               tag | (u64)__float_as_uint(wx),
                               __ATOMIC_RELAXED, __HIP_MEMORY_SCOPE_AGENT);
            __hip_atomic_store(&sb[(2 * WPB + wg) * LINE_U64],
                               tag | (u64)__float_as_uint(wy),
                               __ATOMIC_RELAXED, __HIP_MEMORY_SCOPE_AGENT);
            __hip_atomic_store(&sb[(3 * WPB + wg) * LINE_U64],
                               tag | (u64)__float_as_uint(wz),
                               __ATOMIC_RELAXED, __HIP_MEMORY_SCOPE_AGENT);
        }

        // ---- poll: every wave, lane l watches word l (line l) ----
        u64 v;
        u64* mem = &sb[lane * LINE_U64];
        for (;;) {
            v = __hip_atomic_load(mem, __ATOMIC_RELAXED,
                                  __HIP_MEMORY_SCOPE_AGENT);
            if ((v >> 48) == (u64)it) break;
        }
        // slot s: word0 at lane s, x at 16+s, y at 32+s, z at 48+s
        int sidx = lane & 15;
        u64 cand = __shfl(v, sidx, 64);
        int ws = sidx;
        for (int off = 1; off < 16; off <<= 1) {
            u64 oc = __shfl_xor(cand, off, 64);
            int os = __shfl_xor(ws, off, 64);
            if (oc > cand) { cand = oc; ws = os; }
        }
        cx = __uint_as_float((unsigned)__shfl(v, 16 + ws, 64));
        cy = __uint_as_float((unsigned)__shfl(v, 32 + ws, 64));
        cz = __uint_as_float((unsigned)__shfl(v, 48 + ws, 64));
        if (tid == 0) sel[it] = 0xFFFF - (int)(cand & 0xFFFFull);
    }
    __syncthreads();

    // ---- gather: this WG writes samples [wg*32, wg*32+32) ----
    const float* bf   = feat + (size_t)b * NPTS * 64;
    float*       oxyz = out + (size_t)b * NS * 3;
    float*       of   = out + (size_t)NB * NS * 3 + (size_t)b * NS * 64;
    const int c  = tid & 63;
    const int sr = tid >> 6;
    for (int k = 0; k < SPW / NWAVE; ++k) {
        int s = wg * SPW + k * NWAVE + sr;
        int p = sel[s];
        of[(size_t)s * 64 + c] = bf[(size_t)p * 64 + c];
    }
    if (tid < SPW * 3) {
        int s    = wg * SPW + tid / 3;
        int comp = tid % 3;
        oxyz[s * 3 + comp] = bx[sel[s] * 3 + comp];
    }
}

extern "C" void kernel_launch(void* const* d_in, const int* in_sizes, int n_in,
                              void* d_out, int out_size, void* d_ws, size_t ws_size,
                              hipStream_t stream) {
    const float* xyz = (const float*)d_in[0];
    const float* f   = (const float*)d_in[1];
    float* out = (float*)d_out;
    u64* slots = (u64*)d_ws;
    // Clear tags (tag 0 never matches it>=1). 2 parities x 16 batches x 64
    // lines x 128B = 256 KB.
    hipMemsetAsync(d_ws, 0, (size_t)2 * NB * REGION_U64 * sizeof(u64), stream);
    fps_kernel<<<dim3(NB * WPB), dim3(NTHR), 0, stream>>>(xyz, f, out, slots);
}